// Round 1
// baseline (133.428 us; speedup 1.0000x reference)
//
#include <hip/hip_runtime.h>

#define NQ  12
#define DIM 4096
#define TPB 256

__device__ __forceinline__ float wave_reduce(float v) {
#pragma unroll
    for (int m = 32; m >= 1; m >>= 1) v += __shfl_xor(v, m, 64);
    return v;
}

// One circuit layer q: H on control bit MC (all elements), then
// (X*RX if XGATE else RX) on target bit MT where control bit == 1.
// Works on a 16-element register chunk whose 4 index bits are the 4 qubit
// bits this pass owns. ct = cos(theta/2), sn = sin(theta/2); s = -i*sn.
template <int MC, int MT, bool XGATE>
__device__ __forceinline__ void apply_layer(float2* a, float ct, float sn) {
    const float h = 0.70710678118654752440f;
#pragma unroll
    for (int i = 0; i < 16; ++i) {
        if (i & MC) continue;
        const int j = i | MC;
        const float2 t0 = a[i], t1 = a[j];
        a[i] = make_float2(h * (t0.x + t1.x), h * (t0.y + t1.y));
        a[j] = make_float2(h * (t0.x - t1.x), h * (t0.y - t1.y));
    }
#pragma unroll
    for (int i = 0; i < 16; ++i) {
        if (!(i & MC) || (i & MT)) continue;   // control=1, target=0 slot
        const int j = i | MT;
        const float2 b0 = a[i], b1 = a[j];
        // s*z = (sn*z.y, -sn*z.x)   (s = -i*sn, pure imaginary)
        const float s0x = sn * b0.y, s0y = -sn * b0.x;
        const float s1x = sn * b1.y, s1y = -sn * b1.x;
        if (XGATE) {
            // X*RX = [[s, c],[c, s]]
            a[i] = make_float2(fmaf(ct, b1.x, s0x), fmaf(ct, b1.y, s0y));
            a[j] = make_float2(fmaf(ct, b0.x, s1x), fmaf(ct, b0.y, s1y));
        } else {
            // RX = [[c, s],[s, c]]
            a[i] = make_float2(fmaf(ct, b0.x, s1x), fmaf(ct, b0.y, s1y));
            a[j] = make_float2(fmaf(ct, b1.x, s0x), fmaf(ct, b1.y, s0y));
        }
    }
}

__global__ __launch_bounds__(TPB) void qlayer_kernel(
        const float* __restrict__ state, const float* __restrict__ params,
        float* __restrict__ out) {
    __shared__ float2 amp[DIM];          // 32 KB statevector
    __shared__ float red1[4], red2[4];
    __shared__ float cth[NQ], sth[NQ];

    const int t = threadIdx.x;
    const long long sbase = (long long)blockIdx.x * DIM;

    if (t < NQ) {
        const float th = params[t] * 0.5f;
        cth[t] = cosf(th);
        sth[t] = sinf(th);
    }

    // ---- load 16 contiguous floats (64 B/thread, fully covered) ----
    float x[16];
    const float4* gp = (const float4*)(state + sbase + t * 16);
#pragma unroll
    for (int j = 0; j < 4; ++j) {
        const float4 v = gp[j];
        x[4 * j + 0] = v.x; x[4 * j + 1] = v.y;
        x[4 * j + 2] = v.z; x[4 * j + 3] = v.w;
    }
    float ss = 0.f;
#pragma unroll
    for (int k = 0; k < 16; ++k) ss = fmaf(x[k], x[k], ss);
    ss = wave_reduce(ss);
    const int wid = t >> 6;
    if ((t & 63) == 0) red1[wid] = ss;
    __syncthreads();
    const float nrm  = sqrtf(red1[0] + red1[1] + red1[2] + red1[3]);
    const float invd = 1.0f / (nrm + 1e-8f);

    // ---- classical -> quantum encoding (in registers) ----
    float2 a[16];
    float n2 = 0.f;
#pragma unroll
    for (int k = 0; k < 16; ++k) {
        const float v   = x[k] * invd;
        const float mag = fminf(fabsf(v), 1.0f);
        const float sgn = (v > 0.f) ? 1.f : ((v < 0.f) ? -1.f : 0.f);
        const float re  = sgn * mag;
        const float im  = sgn * sqrtf(fmaxf(1.0f - mag * mag, 0.f));
        a[k] = make_float2(re, im);
        n2 += re * re + im * im;
    }
    n2 = wave_reduce(n2);
    if ((t & 63) == 0) red2[wid] = n2;
    __syncthreads();
    const float inv2 = 1.0f / (red2[0] + red2[1] + red2[2] + red2[3]);

    // ---- pass 1: layers 0..2 on bits {0,1,2,3}; regs hold idx = 16t + r ----
    apply_layer<1, 2, true>(a, cth[0], sth[0]);
    apply_layer<2, 4, true>(a, cth[1], sth[1]);
    apply_layer<4, 8, true>(a, cth[2], sth[2]);
#pragma unroll
    for (int r = 0; r < 16; ++r) amp[t * 16 + r] = a[r];
    __syncthreads();

    // ---- pass 2: layers 3..5 on bits {3,4,5,6} ----
    {
        const int base = (t & 7) | ((t >> 3) << 7);
#pragma unroll
        for (int r = 0; r < 16; ++r) a[r] = amp[base | (r << 3)];
        apply_layer<1, 2, true>(a, cth[3], sth[3]);
        apply_layer<2, 4, true>(a, cth[4], sth[4]);
        apply_layer<4, 8, true>(a, cth[5], sth[5]);
#pragma unroll
        for (int r = 0; r < 16; ++r) amp[base | (r << 3)] = a[r];
    }
    __syncthreads();

    // ---- pass 3: layers 6..8 on bits {6,7,8,9} ----
    {
        const int base = (t & 63) | ((t >> 6) << 10);
#pragma unroll
        for (int r = 0; r < 16; ++r) a[r] = amp[base | (r << 6)];
        apply_layer<1, 2, true>(a, cth[6], sth[6]);
        apply_layer<2, 4, true>(a, cth[7], sth[7]);
        apply_layer<4, 8, true>(a, cth[8], sth[8]);
#pragma unroll
        for (int r = 0; r < 16; ++r) amp[base | (r << 6)] = a[r];
    }
    __syncthreads();

    // ---- pass 4: layers 9..11 on bits {9,10,11,0}; L11 = CRX(c=11,t=0) ----
    {
        const int base = t << 1;  // bits 1..8
#pragma unroll
        for (int r = 0; r < 16; ++r)
            a[r] = amp[base | ((r & 7) << 9) | (r >> 3)];
        apply_layer<1, 2, true >(a, cth[9],  sth[9]);   // c=bit9,  t=bit10
        apply_layer<2, 4, true >(a, cth[10], sth[10]);  // c=bit10, t=bit11
        apply_layer<4, 8, false>(a, cth[11], sth[11]);  // c=bit11, t=bit0 (RX only)

        // probs epilogue: pair (bit0=0, bit0=1) -> contiguous float2 store
        float2* outp = (float2*)(out + sbase);
#pragma unroll
        for (int r = 0; r < 8; ++r) {
            const int idx = base | ((r & 7) << 9);  // even
            const float p0 = (a[r].x * a[r].x + a[r].y * a[r].y) * inv2;
            const float p1 = (a[r | 8].x * a[r | 8].x + a[r | 8].y * a[r | 8].y) * inv2;
            outp[idx >> 1] = make_float2(p0, p1);
        }
    }
}

extern "C" void kernel_launch(void* const* d_in, const int* in_sizes, int n_in,
                              void* d_out, int out_size, void* d_ws, size_t ws_size,
                              hipStream_t stream) {
    (void)in_sizes; (void)n_in; (void)out_size; (void)d_ws; (void)ws_size;
    const float* state  = (const float*)d_in[0];   // (8,512,4096) fp32
    const float* params = (const float*)d_in[1];   // (12,) fp32
    float* out = (float*)d_out;                    // (8,512,4096) fp32
    qlayer_kernel<<<dim3(4096), dim3(TPB), 0, stream>>>(state, params, out);
}

// Round 2
// 128.700 us; speedup vs baseline: 1.0367x; 1.0367x over previous
//
#include <hip/hip_runtime.h>

#define NQ  12
#define DIM 4096
#define TPB 256

// XOR swizzle on float-plane index: bank = SW(i)&31; verified per-pass that
// every bank gets exactly 2 of 64 lanes (wave64 minimum => conflict-free).
__device__ __forceinline__ int SW(int i) { return i ^ ((i >> 5) & 31); }

__device__ __forceinline__ float wave_reduce(float v) {
#pragma unroll
    for (int m = 32; m >= 1; m >>= 1) v += __shfl_xor(v, m, 64);
    return v;
}

// broadcast lane q's value to all lanes via readlane (lands in SGPR)
#define BCAST(v, q) __uint_as_float(__builtin_amdgcn_readlane(__float_as_uint(v), (q)))

// One circuit layer: unnormalized H (no 1/sqrt2 -- folded into epilogue) on
// register-bit MC, then (X*RX if XGATE else RX) on bit MT where MC==1.
// ct = cos(theta/2), sn = sin(theta/2); off-diag s = -i*sn.
template <int MC, int MT, bool XGATE>
__device__ __forceinline__ void apply_layer(float2* a, float ct, float sn) {
#pragma unroll
    for (int i = 0; i < 16; ++i) {
        if (i & MC) continue;
        const int j = i | MC;
        const float2 t0 = a[i], t1 = a[j];
        a[i] = make_float2(t0.x + t1.x, t0.y + t1.y);
        a[j] = make_float2(t0.x - t1.x, t0.y - t1.y);
    }
#pragma unroll
    for (int i = 0; i < 16; ++i) {
        if (!(i & MC) || (i & MT)) continue;   // control=1, target=0 slot
        const int j = i | MT;
        const float2 b0 = a[i], b1 = a[j];
        // s*z = (sn*z.y, -sn*z.x)   (s = -i*sn, pure imaginary)
        const float s0x = sn * b0.y, s0y = -sn * b0.x;
        const float s1x = sn * b1.y, s1y = -sn * b1.x;
        if (XGATE) {
            // X*RX = [[s, c],[c, s]]
            a[i] = make_float2(fmaf(ct, b1.x, s0x), fmaf(ct, b1.y, s0y));
            a[j] = make_float2(fmaf(ct, b0.x, s1x), fmaf(ct, b0.y, s1y));
        } else {
            // RX = [[c, s],[s, c]]
            a[i] = make_float2(fmaf(ct, b0.x, s1x), fmaf(ct, b0.y, s1y));
            a[j] = make_float2(fmaf(ct, b1.x, s0x), fmaf(ct, b1.y, s0y));
        }
    }
}

__global__ __launch_bounds__(TPB) void qlayer_kernel(
        const float* __restrict__ state, const float* __restrict__ params,
        float* __restrict__ out) {
    // exactly 32768 B of LDS -> 5 blocks/CU
    __shared__ float sre[DIM];
    __shared__ float sim[DIM];

    const int t = threadIdx.x;
    const int lane = t & 63;
    const long long sbase = (long long)blockIdx.x * DIM;

    // per-lane angle (lanes 0..11 hold cos/sin(theta_q/2)); broadcast via readlane
    const float th = params[lane < NQ ? lane : 0] * 0.5f;
    const float cl = cosf(th);
    const float sl = sinf(th);

    // ---- load 16 contiguous floats (64 B/thread) + norm reduction ----
    float x[16];
    const float4* gp = (const float4*)(state + sbase + t * 16);
    float ss = 0.f;
#pragma unroll
    for (int j = 0; j < 4; ++j) {
        const float4 v = gp[j];
        x[4 * j + 0] = v.x; x[4 * j + 1] = v.y;
        x[4 * j + 2] = v.z; x[4 * j + 3] = v.w;
        ss = fmaf(v.x, v.x, ss); ss = fmaf(v.y, v.y, ss);
        ss = fmaf(v.z, v.z, ss); ss = fmaf(v.w, v.w, ss);
    }
    ss = wave_reduce(ss);
    if (lane == 0) sre[t >> 6] = ss;     // scratch (overwritten by pass 1)
    __syncthreads();
    const float nrm  = sqrtf(sre[0] + sre[1] + sre[2] + sre[3]);
    const float invd = 1.0f / (nrm + 1e-8f);
    __syncthreads();                     // protect scratch before pass-1 writes

    // ---- encoding: re = clamp(v,-1,1); im = sign(v)*sqrt(1-re^2) ----
    // |q|^2 == 1 exactly => second normalization is 1/4096, folded below.
    float2 a[16];
#pragma unroll
    for (int k = 0; k < 16; ++k) {
        const float v   = x[k] * invd;
        const float re  = fminf(fmaxf(v, -1.0f), 1.0f);
        const float imb = sqrtf(fmaxf(1.0f - re * re, 0.f));
        const float im  = (v > 0.f) ? imb : ((v < 0.f) ? -imb : 0.f);
        a[k] = make_float2(re, im);
    }

    // ---- pass 1: layers 0..2 on idx bits {0,1,2,3}; idx = 16t + r ----
    apply_layer<1, 2, true>(a, BCAST(cl, 0), BCAST(sl, 0));
    apply_layer<2, 4, true>(a, BCAST(cl, 1), BCAST(sl, 1));
    apply_layer<4, 8, true>(a, BCAST(cl, 2), BCAST(sl, 2));
#pragma unroll
    for (int r = 0; r < 16; ++r) {
        const int s = SW(t * 16 + r);
        sre[s] = a[r].x; sim[s] = a[r].y;
    }
    __syncthreads();

    // ---- pass 2: layers 3..5 on idx bits {3,4,5,6} ----
    {
        const int base = (t & 7) | ((t >> 3) << 7);
#pragma unroll
        for (int r = 0; r < 16; ++r) {
            const int s = SW(base | (r << 3));
            a[r] = make_float2(sre[s], sim[s]);
        }
        apply_layer<1, 2, true>(a, BCAST(cl, 3), BCAST(sl, 3));
        apply_layer<2, 4, true>(a, BCAST(cl, 4), BCAST(sl, 4));
        apply_layer<4, 8, true>(a, BCAST(cl, 5), BCAST(sl, 5));
#pragma unroll
        for (int r = 0; r < 16; ++r) {
            const int s = SW(base | (r << 3));
            sre[s] = a[r].x; sim[s] = a[r].y;
        }
    }
    __syncthreads();

    // ---- pass 3: layers 6..8 on idx bits {6,7,8,9} ----
    {
        const int base = (t & 63) | ((t >> 6) << 10);
#pragma unroll
        for (int r = 0; r < 16; ++r) {
            const int s = SW(base | (r << 6));
            a[r] = make_float2(sre[s], sim[s]);
        }
        apply_layer<1, 2, true>(a, BCAST(cl, 6), BCAST(sl, 6));
        apply_layer<2, 4, true>(a, BCAST(cl, 7), BCAST(sl, 7));
        apply_layer<4, 8, true>(a, BCAST(cl, 8), BCAST(sl, 8));
#pragma unroll
        for (int r = 0; r < 16; ++r) {
            const int s = SW(base | (r << 6));
            sre[s] = a[r].x; sim[s] = a[r].y;
        }
    }
    __syncthreads();

    // ---- pass 4: layers 9..11 on idx bits {9,10,11,0}; L11 = CRX only ----
    {
        const int base = t << 1;  // idx bits 1..8
#pragma unroll
        for (int r = 0; r < 16; ++r) {
            const int s = SW(base | ((r & 7) << 9) | (r >> 3));
            a[r] = make_float2(sre[s], sim[s]);
        }
        apply_layer<1, 2, true >(a, BCAST(cl, 9),  BCAST(sl, 9));   // c=b9,  t=b10
        apply_layer<2, 4, true >(a, BCAST(cl, 10), BCAST(sl, 10));  // c=b10, t=b11
        apply_layer<4, 8, false>(a, BCAST(cl, 11), BCAST(sl, 11));  // c=b11, t=b0

        // probs epilogue; scale = 1/4096 (encode norm) * (1/sqrt2)^24 = 2^-24
        const float scale = 0x1p-24f;
        float2* outp = (float2*)(out + sbase);
#pragma unroll
        for (int r = 0; r < 8; ++r) {
            const int idx = base | ((r & 7) << 9);  // even (bit0 = 0)
            const float p0 = (a[r].x * a[r].x + a[r].y * a[r].y) * scale;
            const float p1 = (a[r | 8].x * a[r | 8].x + a[r | 8].y * a[r | 8].y) * scale;
            outp[idx >> 1] = make_float2(p0, p1);
        }
    }
}

extern "C" void kernel_launch(void* const* d_in, const int* in_sizes, int n_in,
                              void* d_out, int out_size, void* d_ws, size_t ws_size,
                              hipStream_t stream) {
    (void)in_sizes; (void)n_in; (void)out_size; (void)d_ws; (void)ws_size;
    const float* state  = (const float*)d_in[0];   // (8,512,4096) fp32
    const float* params = (const float*)d_in[1];   // (12,) fp32
    float* out = (float*)d_out;                    // (8,512,4096) fp32
    qlayer_kernel<<<dim3(4096), dim3(TPB), 0, stream>>>(state, params, out);
}

// Round 3
// 126.906 us; speedup vs baseline: 1.0514x; 1.0141x over previous
//
#include <hip/hip_runtime.h>

#define NQ  12
#define DIM 4096
#define TPB 256

typedef float v2f __attribute__((ext_vector_type(2)));

// Per-phase (32-lane) conflict-free XOR swizzles, verified per access pattern:
// SW4 is bijective-per-half for pass1-write/pass2-read/pass2-write/pass3-read;
// SW5 for pass3-write/pass4-read. A swizzle only has to match between a write
// and the read of the same round-trip.
__device__ __forceinline__ int SW4(int i) { return i ^ ((i >> 4) & 31); }
__device__ __forceinline__ int SW5(int i) { return i ^ ((i >> 5) & 31); }

__device__ __forceinline__ float wave_reduce(float v) {
#pragma unroll
    for (int m = 32; m >= 1; m >>= 1) v += __shfl_xor(v, m, 64);
    return v;
}

// broadcast lane q's value to all lanes (lands in SGPR)
#define BCAST(v, q) __uint_as_float(__builtin_amdgcn_readlane(__float_as_uint(v), (q)))

// One circuit layer: unnormalized H on register-bit MC (1/sqrt2 folded into
// epilogue), then (X*RX if XGATE else RX) on bit MT where MC==1.
// ctv = (c,c), snv = (s,-s) with c=cos(th/2), s=sin(th/2); off-diag = -i*s,
// so (-i*s)*z = (s*z.y, -s*z.x) = snv * z.yx  -> one v_pk_mul_f32.
template <int MC, int MT, bool XGATE>
__device__ __forceinline__ void apply_layer(v2f* a, v2f ctv, v2f snv) {
#pragma unroll
    for (int i = 0; i < 16; ++i) {
        if (i & MC) continue;
        const int j = i | MC;
        const v2f t0 = a[i], t1 = a[j];
        a[i] = t0 + t1;          // v_pk_add_f32
        a[j] = t0 - t1;          // v_pk_add_f32 (neg)
    }
#pragma unroll
    for (int i = 0; i < 16; ++i) {
        if (!(i & MC) || (i & MT)) continue;   // control=1, target=0 slot
        const int j = i | MT;
        const v2f b0 = a[i], b1 = a[j];
        const v2f s0 = snv * b0.yx;            // v_pk_mul_f32
        const v2f s1 = snv * b1.yx;
        if (XGATE) {                           // X*RX = [[s, c],[c, s]]
            a[i] = ctv * b1 + s0;              // v_pk_fma_f32
            a[j] = ctv * b0 + s1;
        } else {                               // RX = [[c, s],[s, c]]
            a[i] = ctv * b0 + s1;
            a[j] = ctv * b1 + s0;
        }
    }
}

__global__ __launch_bounds__(TPB) void qlayer_kernel(
        const float* __restrict__ state, const float* __restrict__ params,
        float* __restrict__ out) {
    // exactly 32768 B of LDS
    __shared__ float sre[DIM];
    __shared__ float sim[DIM];

    const int t = threadIdx.x;
    const int lane = t & 63;
    const long long sbase = (long long)blockIdx.x * DIM;

    // per-lane angle (lanes 0..11 hold cos/sin(theta_q/2)); broadcast via readlane
    const float th = params[lane < NQ ? lane : 0] * 0.5f;
    const float cl = cosf(th);
    const float sl = sinf(th);

    // ---- load 16 contiguous floats (64 B/thread) + norm reduction ----
    float x[16];
    const float4* gp = (const float4*)(state + sbase + t * 16);
    float ss = 0.f;
#pragma unroll
    for (int j = 0; j < 4; ++j) {
        const float4 v = gp[j];
        x[4 * j + 0] = v.x; x[4 * j + 1] = v.y;
        x[4 * j + 2] = v.z; x[4 * j + 3] = v.w;
        ss = fmaf(v.x, v.x, ss); ss = fmaf(v.y, v.y, ss);
        ss = fmaf(v.z, v.z, ss); ss = fmaf(v.w, v.w, ss);
    }
    ss = wave_reduce(ss);
    if (lane == 0) sre[t >> 6] = ss;     // scratch (overwritten by pass 1)
    __syncthreads();
    const float nrm  = sqrtf(sre[0] + sre[1] + sre[2] + sre[3]);
    const float invd = 1.0f / (nrm + 1e-8f);
    __syncthreads();                     // protect scratch before pass-1 writes

    // ---- encoding: re = clamp(v,-1,1); im = sign(v)*sqrt(1-re^2) ----
    // |q|^2 == 1 exactly => second normalization = 1/4096, folded into epilogue.
    v2f a[16];
#pragma unroll
    for (int k = 0; k < 16; ++k) {
        const float v   = x[k] * invd;
        const float re  = fminf(fmaxf(v, -1.0f), 1.0f);
        const float imb = sqrtf(fmaxf(1.0f - re * re, 0.f));
        const float im  = (v > 0.f) ? imb : ((v < 0.f) ? -imb : 0.f);
        v2f q; q.x = re; q.y = im;
        a[k] = q;
    }

#define CTV(q) ({ v2f _c; _c.x = BCAST(cl, q); _c.y = _c.x; _c; })
#define SNV(q) ({ float _s = BCAST(sl, q); v2f _v; _v.x = _s; _v.y = -_s; _v; })

    // ---- pass 1: layers 0..2 on idx bits {0,1,2,3}; idx = 16t + r ----
    apply_layer<1, 2, true>(a, CTV(0), SNV(0));
    apply_layer<2, 4, true>(a, CTV(1), SNV(1));
    apply_layer<4, 8, true>(a, CTV(2), SNV(2));
#pragma unroll
    for (int r = 0; r < 16; ++r) {
        const int s = SW4(t * 16 + r);
        sre[s] = a[r].x; sim[s] = a[r].y;
    }
    __syncthreads();

    // ---- pass 2: layers 3..5 on idx bits {3,4,5,6} ----
    {
        const int base = (t & 7) | ((t >> 3) << 7);
        int sa[16];
#pragma unroll
        for (int r = 0; r < 16; ++r) {
            sa[r] = SW4(base | (r << 3));
            v2f q; q.x = sre[sa[r]]; q.y = sim[sa[r]];
            a[r] = q;
        }
        apply_layer<1, 2, true>(a, CTV(3), SNV(3));
        apply_layer<2, 4, true>(a, CTV(4), SNV(4));
        apply_layer<4, 8, true>(a, CTV(5), SNV(5));
#pragma unroll
        for (int r = 0; r < 16; ++r) {
            sre[sa[r]] = a[r].x; sim[sa[r]] = a[r].y;
        }
    }
    __syncthreads();

    // ---- pass 3: layers 6..8 on idx bits {6,7,8,9}; read SW4, write SW5 ----
    {
        const int base = (t & 63) | ((t >> 6) << 10);
#pragma unroll
        for (int r = 0; r < 16; ++r) {
            const int s = SW4(base | (r << 6));
            v2f q; q.x = sre[s]; q.y = sim[s];
            a[r] = q;
        }
        apply_layer<1, 2, true>(a, CTV(6), SNV(6));
        apply_layer<2, 4, true>(a, CTV(7), SNV(7));
        apply_layer<4, 8, true>(a, CTV(8), SNV(8));
#pragma unroll
        for (int r = 0; r < 16; ++r) {
            const int s = SW5(base | (r << 6));
            sre[s] = a[r].x; sim[s] = a[r].y;
        }
    }
    __syncthreads();

    // ---- pass 4: layers 9..11 on idx bits {9,10,11,0}; L11 = CRX only ----
    {
        const int base = t << 1;  // idx bits 1..8
#pragma unroll
        for (int r = 0; r < 16; ++r) {
            const int s = SW5(base | ((r & 7) << 9) | (r >> 3));
            v2f q; q.x = sre[s]; q.y = sim[s];
            a[r] = q;
        }
        apply_layer<1, 2, true >(a, CTV(9),  SNV(9));   // c=b9,  t=b10
        apply_layer<2, 4, true >(a, CTV(10), SNV(10));  // c=b10, t=b11
        apply_layer<4, 8, false>(a, CTV(11), SNV(11));  // c=b11, t=b0

        // probs epilogue; scale = 1/4096 (encode norm) * (1/sqrt2)^24 = 2^-24
        const float scale = 0x1p-24f;
        float2* outp = (float2*)(out + sbase);
#pragma unroll
        for (int r = 0; r < 8; ++r) {
            const int idx = base | ((r & 7) << 9);  // even (bit0 = 0)
            const v2f q0 = a[r] * a[r];             // v_pk_mul_f32
            const v2f q1 = a[r | 8] * a[r | 8];
            outp[idx >> 1] = make_float2((q0.x + q0.y) * scale,
                                         (q1.x + q1.y) * scale);
        }
    }
#undef CTV
#undef SNV
}

extern "C" void kernel_launch(void* const* d_in, const int* in_sizes, int n_in,
                              void* d_out, int out_size, void* d_ws, size_t ws_size,
                              hipStream_t stream) {
    (void)in_sizes; (void)n_in; (void)out_size; (void)d_ws; (void)ws_size;
    const float* state  = (const float*)d_in[0];   // (8,512,4096) fp32
    const float* params = (const float*)d_in[1];   // (12,) fp32
    float* out = (float*)d_out;                    // (8,512,4096) fp32
    qlayer_kernel<<<dim3(4096), dim3(TPB), 0, stream>>>(state, params, out);
}

// Round 4
// 121.324 us; speedup vs baseline: 1.0998x; 1.0460x over previous
//
#include <hip/hip_runtime.h>

#define NQ  12
#define DIM 4096
#define TPB 256

typedef float v2f __attribute__((ext_vector_type(2)));
typedef float v4f __attribute__((ext_vector_type(4)));

// Padded LDS layout for interleaved float2 amplitudes:
//   slot(e) = e + 2*(e>>5)            (2 pad elements per 32)
// Verified per 32-lane phase for all four pass patterns: b64 accesses are
// exactly 2 lanes/bank-pair, b128 accesses exactly 4 lanes/bank-quad
// (= the hardware minimum, i.e. conflict-free). In every pass
// slot = thread_base + compile-time-const(r), so per-r offsets fold into
// the ds instruction offset immediate (no per-access VALU address math).

__device__ __forceinline__ float wave_reduce(float v) {
#pragma unroll
    for (int m = 32; m >= 1; m >>= 1) v += __shfl_xor(v, m, 64);
    return v;
}

// broadcast lane q's value to all lanes (lands in SGPR)
#define BCAST(v, q) __uint_as_float(__builtin_amdgcn_readlane(__float_as_uint(v), (q)))

// One circuit layer: unnormalized H on register-bit MC (1/sqrt2 folded into
// epilogue), then (X*RX if XGATE else RX) on bit MT where MC==1.
// ctv = (c,c), snv = (s,-s); off-diag = -i*s, so (-i*s)*z = snv * z.yx.
template <int MC, int MT, bool XGATE>
__device__ __forceinline__ void apply_layer(v2f* a, v2f ctv, v2f snv) {
#pragma unroll
    for (int i = 0; i < 16; ++i) {
        if (i & MC) continue;
        const int j = i | MC;
        const v2f t0 = a[i], t1 = a[j];
        a[i] = t0 + t1;          // v_pk_add_f32
        a[j] = t0 - t1;
    }
#pragma unroll
    for (int i = 0; i < 16; ++i) {
        if (!(i & MC) || (i & MT)) continue;   // control=1, target=0 slot
        const int j = i | MT;
        const v2f b0 = a[i], b1 = a[j];
        const v2f s0 = snv * b0.yx;            // v_pk_mul_f32
        const v2f s1 = snv * b1.yx;
        if (XGATE) {                           // X*RX = [[s, c],[c, s]]
            a[i] = ctv * b1 + s0;              // v_pk_fma_f32
            a[j] = ctv * b0 + s1;
        } else {                               // RX = [[c, s],[s, c]]
            a[i] = ctv * b0 + s1;
            a[j] = ctv * b1 + s0;
        }
    }
}

__global__ __launch_bounds__(TPB, 4) void qlayer_kernel(
        const float* __restrict__ state, const float* __restrict__ params,
        float* __restrict__ out) {
    __shared__ __align__(16) v2f amp[DIM + 256];   // 34816 B, padded layout
    __shared__ float red[4];

    const int t = threadIdx.x;
    const int lane = t & 63;
    const long long sbase = (long long)blockIdx.x * DIM;

    // per-lane angle (lanes 0..11 hold cos/sin(theta_q/2)); broadcast via readlane
    const float th = params[lane < NQ ? lane : 0] * 0.5f;
    const float cl = cosf(th);
    const float sl = sinf(th);

    // ---- load 16 contiguous floats (64 B/thread) + norm reduction ----
    float x[16];
    const float4* gp = (const float4*)(state + sbase + t * 16);
    float ss = 0.f;
#pragma unroll
    for (int j = 0; j < 4; ++j) {
        const float4 v = gp[j];
        x[4 * j + 0] = v.x; x[4 * j + 1] = v.y;
        x[4 * j + 2] = v.z; x[4 * j + 3] = v.w;
        ss = fmaf(v.x, v.x, ss); ss = fmaf(v.y, v.y, ss);
        ss = fmaf(v.z, v.z, ss); ss = fmaf(v.w, v.w, ss);
    }
    ss = wave_reduce(ss);
    if (lane == 0) red[t >> 6] = ss;
    __syncthreads();
    const float nrm  = sqrtf(red[0] + red[1] + red[2] + red[3]);
    const float invd = 1.0f / (nrm + 1e-8f);

    // ---- encoding: re = clamp(v,-1,1); im = sign(v)*sqrt(1-re^2) ----
    // |q|^2 == 1 exactly => second normalization = 1/4096, folded into epilogue.
    v2f a[16];
#pragma unroll
    for (int k = 0; k < 16; ++k) {
        const float v   = x[k] * invd;
        const float re  = fminf(fmaxf(v, -1.0f), 1.0f);
        const float imb = sqrtf(fmaxf(1.0f - re * re, 0.f));
        const float im  = (v > 0.f) ? imb : ((v < 0.f) ? -imb : 0.f);
        v2f q; q.x = re; q.y = im;
        a[k] = q;
    }

#define CTV(q) ({ v2f _c; _c.x = BCAST(cl, q); _c.y = _c.x; _c; })
#define SNV(q) ({ float _s = BCAST(sl, q); v2f _v; _v.x = _s; _v.y = -_s; _v; })

    // ---- pass 1: layers 0..2 on idx bits {0,1,2,3}; e = 16t + r ----
    apply_layer<1, 2, true>(a, CTV(0), SNV(0));
    apply_layer<2, 4, true>(a, CTV(1), SNV(1));
    apply_layer<4, 8, true>(a, CTV(2), SNV(2));
    {
        // slot = 16t + 2*(t>>1) + r ; write pairs as b128
        const int p1base = 16 * t + 2 * (t >> 1);
#pragma unroll
        for (int k = 0; k < 8; ++k) {
            v4f w; w.x = a[2 * k].x; w.y = a[2 * k].y;
            w.z = a[2 * k + 1].x; w.w = a[2 * k + 1].y;
            *(v4f*)&amp[p1base + 2 * k] = w;
        }
    }
    __syncthreads();

    // ---- pass 2: layers 3..5 on idx bits {3,4,5,6}; e = base2 + 8r ----
    {
        // slot = (t&7) + 136*(t>>3) + [8r + 2*(r>>2)]
        const int p2base = (t & 7) + 136 * (t >> 3);
#pragma unroll
        for (int r = 0; r < 16; ++r)
            a[r] = amp[p2base + 8 * r + 2 * (r >> 2)];
        apply_layer<1, 2, true>(a, CTV(3), SNV(3));
        apply_layer<2, 4, true>(a, CTV(4), SNV(4));
        apply_layer<4, 8, true>(a, CTV(5), SNV(5));
#pragma unroll
        for (int r = 0; r < 16; ++r)
            amp[p2base + 8 * r + 2 * (r >> 2)] = a[r];
    }
    __syncthreads();

    // ---- pass 3: layers 6..8 on idx bits {6,7,8,9}; e = base3 + 64r ----
    {
        // slot = (t&63) + 2*((t&63)>>5) + 1088*(t>>6) + 68r
        const int p3base = (t & 63) + 2 * ((t & 63) >> 5) + 1088 * (t >> 6);
#pragma unroll
        for (int r = 0; r < 16; ++r)
            a[r] = amp[p3base + 68 * r];
        apply_layer<1, 2, true>(a, CTV(6), SNV(6));
        apply_layer<2, 4, true>(a, CTV(7), SNV(7));
        apply_layer<4, 8, true>(a, CTV(8), SNV(8));
#pragma unroll
        for (int r = 0; r < 16; ++r)
            amp[p3base + 68 * r] = a[r];
    }
    __syncthreads();

    // ---- pass 4: layers 9..11 on idx bits {9,10,11,0}; e = 2t + 512k + b0 ----
    {
        // slot = 2t + 2*(t>>4) + 544k + b0 ; (b0=0,b0=1) adjacent -> b128
        const int p4base = 2 * t + 2 * (t >> 4);
#pragma unroll
        for (int k = 0; k < 8; ++k) {
            const v4f v = *(const v4f*)&amp[p4base + 544 * k];
            v2f q0; q0.x = v.x; q0.y = v.y;
            v2f q1; q1.x = v.z; q1.y = v.w;
            a[k] = q0;       // bit0 = 0
            a[k + 8] = q1;   // bit0 = 1
        }
        apply_layer<1, 2, true >(a, CTV(9),  SNV(9));   // c=b9,  t=b10
        apply_layer<2, 4, true >(a, CTV(10), SNV(10));  // c=b10, t=b11
        apply_layer<4, 8, false>(a, CTV(11), SNV(11));  // c=b11, t=b0

        // probs epilogue; scale = 1/4096 (encode norm) * (1/sqrt2)^24 = 2^-24
        const float scale = 0x1p-24f;
        float2* outp = (float2*)(out + sbase);
#pragma unroll
        for (int k = 0; k < 8; ++k) {
            const v2f q0 = a[k] * a[k];             // v_pk_mul_f32
            const v2f q1 = a[k | 8] * a[k | 8];
            outp[t + (k << 8)] = make_float2((q0.x + q0.y) * scale,
                                             (q1.x + q1.y) * scale);
        }
    }
#undef CTV
#undef SNV
}

extern "C" void kernel_launch(void* const* d_in, const int* in_sizes, int n_in,
                              void* d_out, int out_size, void* d_ws, size_t ws_size,
                              hipStream_t stream) {
    (void)in_sizes; (void)n_in; (void)out_size; (void)d_ws; (void)ws_size;
    const float* state  = (const float*)d_in[0];   // (8,512,4096) fp32
    const float* params = (const float*)d_in[1];   // (12,) fp32
    float* out = (float*)d_out;                    // (8,512,4096) fp32
    qlayer_kernel<<<dim3(4096), dim3(TPB), 0, stream>>>(state, params, out);
}